// Round 4
// baseline (153.193 us; speedup 1.0000x reference)
//
#include <hip/hip_runtime.h>
#include <hip/hip_bf16.h>
#include <stdint.h>

#define HIDDEN 1024
#define NHEADS 16
#define DHEAD  64
#define BATCH  2
#define SEQ    2048
#define MROWS  (BATCH*SEQ)   // 4096
#define QKVC   (3*HIDDEN)    // 3072

typedef unsigned short u16;
typedef unsigned int   u32;
typedef __bf16 bf16x8 __attribute__((ext_vector_type(8)));
typedef float  f32x4  __attribute__((ext_vector_type(4)));
typedef float  f32x16 __attribute__((ext_vector_type(16)));
typedef short  s16x4  __attribute__((ext_vector_type(4)));
typedef u16    u16x8  __attribute__((ext_vector_type(8)));

typedef const __attribute__((address_space(1))) void gvoid_t;
typedef       __attribute__((address_space(3))) void lvoid_t;

__device__ __forceinline__ gvoid_t* to_glob(const void* p){
  return (gvoid_t*)(uintptr_t)p;
}
__device__ __forceinline__ lvoid_t* to_lds(void* p){
  return (lvoid_t*)(uintptr_t)p;
}
__device__ __forceinline__ u32 lds_off(const void* p){
  return (u32)(uintptr_t)p;
}

__device__ __forceinline__ u16 f2bf(float x){   // RNE f32->bf16
  u32 u = __builtin_bit_cast(u32, x);
  u32 r = (u + 0x7fffu + ((u >> 16) & 1u)) >> 16;
  return (u16)r;
}

// packed f32x2 -> bf16x2 (integer-only; compiler may fuse to v_cvt_pk_bf16_f32)
__device__ __forceinline__ u32 pkbf(float a, float b){
  return (u32)f2bf(a) | ((u32)f2bf(b) << 16);
}

#define MFMA32(a, b, c) __builtin_amdgcn_mfma_f32_32x32x16_bf16(a, b, c, 0, 0, 0)

// ---------------- fp32 -> bf16 conversion ----------------
__global__ __launch_bounds__(256) void k_cvt(const float* __restrict__ in,
                                             u16* __restrict__ out, int n4){
  int i = blockIdx.x * 256 + threadIdx.x;
  if (i >= n4) return;
  const float4 v = reinterpret_cast<const float4*>(in)[i];
  ushort4 o;
  o.x = f2bf(v.x); o.y = f2bf(v.y); o.z = f2bf(v.z); o.w = f2bf(v.w);
  reinterpret_cast<ushort4*>(out)[i] = o;
}

// ---------------- bf16 GEMM, C = A * B^T + bias (unchanged from R2) ----------------
template<int NC, bool BF16OUT>
__global__ __launch_bounds__(256) void k_gemm(const u16* __restrict__ A,
                                              const u16* __restrict__ B,
                                              const float* __restrict__ bias,
                                              void* __restrict__ C){
  constexpr int K = HIDDEN;
  __shared__ u16 As[128*32];
  __shared__ u16 Bs[128*32];
  const int m0 = blockIdx.x * 128;
  const int n0 = blockIdx.y * 128;
  const int tid = threadIdx.x;
  const int w = tid >> 6, l = tid & 63;
  const int wr = w >> 1, wc = w & 1;

  const f32x4 fz = {0.f, 0.f, 0.f, 0.f};
  f32x4 acc[4][4];
  #pragma unroll
  for (int i = 0; i < 4; ++i)
    #pragma unroll
    for (int j = 0; j < 4; ++j) acc[i][j] = fz;

  const u16* ap = A + (size_t)(m0 + (tid >> 2)) * K + (tid & 3) * 8;
  const u16* bp = B + (size_t)(n0 + (tid >> 2)) * K + (tid & 3) * 8;

  for (int k0 = 0; k0 < K; k0 += 32){
    __syncthreads();
    __builtin_amdgcn_global_load_lds(to_glob(ap + k0),          to_lds(&As[w*512]),        16, 0, 0);
    __builtin_amdgcn_global_load_lds(to_glob(ap + 64*K + k0),   to_lds(&As[2048 + w*512]), 16, 0, 0);
    __builtin_amdgcn_global_load_lds(to_glob(bp + k0),          to_lds(&Bs[w*512]),        16, 0, 0);
    __builtin_amdgcn_global_load_lds(to_glob(bp + 64*K + k0),   to_lds(&Bs[2048 + w*512]), 16, 0, 0);
    __syncthreads();

    bf16x8 af[4], bfr[4];
    #pragma unroll
    for (int mf = 0; mf < 4; ++mf)
      af[mf]  = *(const bf16x8*)&As[(wr*64 + mf*16 + (l & 15))*32 + (l >> 4)*8];
    #pragma unroll
    for (int nf = 0; nf < 4; ++nf)
      bfr[nf] = *(const bf16x8*)&Bs[(wc*64 + nf*16 + (l & 15))*32 + (l >> 4)*8];
    #pragma unroll
    for (int mf = 0; mf < 4; ++mf)
      #pragma unroll
      for (int nf = 0; nf < 4; ++nf)
        acc[mf][nf] = __builtin_amdgcn_mfma_f32_16x16x32_bf16(af[mf], bfr[nf], acc[mf][nf], 0, 0, 0);
  }

  #pragma unroll
  for (int nf = 0; nf < 4; ++nf){
    const int col = n0 + wc*64 + nf*16 + (l & 15);
    const float bv = bias[col];
    #pragma unroll
    for (int mf = 0; mf < 4; ++mf){
      #pragma unroll
      for (int r = 0; r < 4; ++r){
        const int row = m0 + wr*64 + mf*16 + (l >> 4)*4 + r;
        const float v = acc[mf][nf][r] + bv;
        if constexpr (BF16OUT) ((u16*)C)[(size_t)row * NC + col] = f2bf(v);
        else                   ((float*)C)[(size_t)row * NC + col] = v;
      }
    }
  }
}

// ---------------- causal flash attention: 32x32 swapped-QK^T, in-register softmax ----
// grid = (32 bh, 32 row-groups), block = 128 (2 waves x 32 q-rows).
// Row-group remapped (0,31,1,30,...) for causal load balance. blockIdx.x=bh keeps
// all blocks of one head on one XCD (linear%8 == bh%8) -> K/V stay L2-resident.
// Per wave: S^T = K.Q^T via mfma_32x32x16 (lane owns q = l&31); softmax in-register;
// P->A-frag via pkbf + shfl(l^32); PV B-frag via ds_read_b64_tr_b16 from subtiled Vs.
__global__ __launch_bounds__(128) void k_attn(const u16* __restrict__ qkv,
                                              u16* __restrict__ aout){
  __shared__ u16 Ks[2][64*64];   // [buf][k][d] row 128B, chunk^(row&7) XOR swizzle
  __shared__ u16 Vs[2][64*64];   // [buf] subtiled: elem(k,d) -> (k>>2)*256+(d>>4)*64+(k&3)*16+(d&15)

  const int bh = blockIdx.x;
  const int b  = bh >> 4;
  const int h  = bh & 15;
  const int yy = blockIdx.y;
  const int ii = (yy & 1) ? (31 - (yy >> 1)) : (yy >> 1);   // balance remap
  const int tid = threadIdx.x;
  const int w = tid >> 6, l = tid & 63;
  const int q0w = ii*64 + w*32;                 // this wave's 32 q-rows
  const size_t base = (size_t)b * SEQ * QKVC + (size_t)h * 192;
  const float CEXP = 0.18033688011112042f;      // 0.125 * log2(e)

  // Q B-frags: col=q=(l&31), k-dim=d=(l>>5)*8 + dd*16 + j
  bf16x8 qf[4];
  {
    const u16* qp = qkv + base + (size_t)(q0w + (l & 31)) * QKVC + (l >> 5) * 8;
    #pragma unroll
    for (int dd = 0; dd < 4; ++dd) qf[dd] = *(const bf16x8*)(qp + dd*16);
  }

  f32x16 o0{}, o1{};              // O[q=row(r)][d=(l&31)+{0,32}]
  float m = -1e30f, lsum = 0.f;   // per-lane state for q = l&31 (half k-coverage)

  auto stageK = [&](int kt, int buf){
    #pragma unroll
    for (int t = 0; t < 4; ++t){
      const int i  = t*128 + tid;
      const int kr = i >> 3;
      const int cg = (i & 7) ^ (kr & 7);     // pre-swizzled global source (rule #21)
      const u16* src = qkv + base + (size_t)(kt*64 + kr) * QKVC + 64 + cg * 8;
      __builtin_amdgcn_global_load_lds(to_glob(src), to_lds(&Ks[buf][t*1024 + w*512]), 16, 0, 0);
    }
  };
  auto loadV = [&](int kt, u16x8* vt){
    #pragma unroll
    for (int t = 0; t < 4; ++t){
      const int i = t*128 + tid;
      const int k = i >> 3, d0 = (i & 7) * 8;
      vt[t] = *(const u16x8*)(qkv + base + (size_t)(kt*64 + k) * QKVC + 128 + d0);
    }
  };
  auto writeV = [&](int buf, const u16x8* vt){
    #pragma unroll
    for (int t = 0; t < 4; ++t){
      const int i = t*128 + tid;
      const int k = i >> 3, d0 = (i & 7) * 8;
      const int eo = (k >> 2)*256 + (d0 >> 4)*64 + (k & 3)*16 + (d0 & 15);
      *(u16x8*)&Vs[buf][eo] = vt[t];
    }
  };

  {  // prologue: tile 0 -> buf 0
    u16x8 vt[4];
    stageK(0, 0);
    loadV(0, vt);
    writeV(0, vt);
  }
  __syncthreads();

  const u32 vbase = lds_off(&Vs[0][0]) + (l & 15)*8 + ((l >> 4) & 1)*128 + (l >> 5)*1024;

  for (int kt = 0; kt <= ii; ++kt){
    const int cur = kt & 1;
    const bool pf = (kt < ii);
    u16x8 vt[4];
    if (pf){ stageK(kt + 1, cur ^ 1); loadV(kt + 1, vt); }   // issue early (T14)

    // ---- QK^T: S^T[k][q], acc0 = k 0..31, acc1 = k 32..63
    f32x16 acc0{}, acc1{};
    #pragma unroll
    for (int dd = 0; dd < 4; ++dd){
      const int r0 = l & 31, r1 = 32 + (l & 31);
      const int c  = dd*2 + (l >> 5);
      const bf16x8 k0 = *(const bf16x8*)&Ks[cur][r0*64 + (c ^ (r0 & 7))*8];
      const bf16x8 k1 = *(const bf16x8*)&Ks[cur][r1*64 + (c ^ (r1 & 7))*8];
      acc0 = MFMA32(k0, qf[dd], acc0);
      acc1 = MFMA32(k1, qf[dd], acc1);
    }

    // ---- causal mask (only the final k-tile is diagonal for both waves)
    if (kt == ii){
      const int qg = q0w + (l & 31);
      #pragma unroll
      for (int r = 0; r < 16; ++r){
        const int kg = kt*64 + (r & 3) + 8*(r >> 2) + 4*(l >> 5);
        if (kg      > qg) acc0[r] = -1e30f;
        if (kg + 32 > qg) acc1[r] = -1e30f;
      }
    }

    // ---- in-register softmax (lane owns q = l&31; local k-half)
    float pm = -1e30f;
    #pragma unroll
    for (int r = 0; r < 16; ++r){
      pm = fmaxf(pm, fmaxf(acc0[r], acc1[r]));
    }
    pm = fmaxf(pm, __shfl(pm, l ^ 32));   // combine k-halves (same q)

    if (__any(pm > m + 64.f)){            // T13 defer-max (THR=64 raw == 8 scaled)
      const float mn = fmaxf(m, pm);
      const float corr = exp2f((m - mn) * CEXP);
      m = mn;
      lsum *= corr;
      #pragma unroll
      for (int r = 0; r < 16; ++r){
        const int row = (r & 3) + 8*(r >> 2) + 4*(l >> 5);
        const float cr = __shfl(corr, row | (l & 32));
        o0[r] *= cr; o1[r] *= cr;
      }
    }
    #pragma unroll
    for (int r = 0; r < 16; ++r){
      const float p0 = exp2f((acc0[r] - m) * CEXP);
      const float p1 = exp2f((acc1[r] - m) * CEXP);
      lsum += p0 + p1;
      acc0[r] = p0; acc1[r] = p1;
    }

    // ---- PV: per kk (16 k): A-frag from P (pkbf + shfl + select), B via tr_read
    const u32 vb = vbase + (cur ? 8192u : 0u);
    #pragma unroll
    for (int kk = 0; kk < 4; ++kk){
      // p-values for this k-block live in acc{T}[8*t2 .. 8*t2+7], T=kk>>1, t2=kk&1
      u32 x0, x1, y0, y1;
      if (kk == 0){ x0=pkbf(acc0[0],acc0[1]); x1=pkbf(acc0[2],acc0[3]); y0=pkbf(acc0[4],acc0[5]); y1=pkbf(acc0[6],acc0[7]); }
      else if (kk == 1){ x0=pkbf(acc0[8],acc0[9]); x1=pkbf(acc0[10],acc0[11]); y0=pkbf(acc0[12],acc0[13]); y1=pkbf(acc0[14],acc0[15]); }
      else if (kk == 2){ x0=pkbf(acc1[0],acc1[1]); x1=pkbf(acc1[2],acc1[3]); y0=pkbf(acc1[4],acc1[5]); y1=pkbf(acc1[6],acc1[7]); }
      else             { x0=pkbf(acc1[8],acc1[9]); x1=pkbf(acc1[10],acc1[11]); y0=pkbf(acc1[12],acc1[13]); y1=pkbf(acc1[14],acc1[15]); }
      const u32 sx0 = __shfl(x0, l ^ 32), sx1 = __shfl(x1, l ^ 32);
      const u32 sy0 = __shfl(y0, l ^ 32), sy1 = __shfl(y1, l ^ 32);
      const bool lo = (l < 32);
      union { u32 wrd[4]; bf16x8 v; } af;
      af.wrd[0] = lo ? x0  : sy0;
      af.wrd[1] = lo ? x1  : sy1;
      af.wrd[2] = lo ? sx0 : y0;
      af.wrd[3] = lo ? sx1 : y1;

      s16x4 t0, t1, t2, t3;
      const u32 va = vb + kk*2048;
      asm volatile("ds_read_b64_tr_b16 %0, %4 offset:0\n\t"     // dh=0, j 0..3
                   "ds_read_b64_tr_b16 %1, %4 offset:512\n\t"   // dh=0, j 4..7
                   "ds_read_b64_tr_b16 %2, %4 offset:256\n\t"   // dh=1, j 0..3
                   "ds_read_b64_tr_b16 %3, %4 offset:768"       // dh=1, j 4..7
                   : "=&v"(t0), "=&v"(t1), "=&v"(t2), "=&v"(t3) : "v"(va));
      asm volatile("s_waitcnt lgkmcnt(0)" ::: "memory");
      __builtin_amdgcn_sched_barrier(0);
      union { s16x4 hh[2]; bf16x8 v; } b0, b1;
      b0.hh[0] = t0; b0.hh[1] = t1;
      b1.hh[0] = t2; b1.hh[1] = t3;
      o0 = MFMA32(af.v, b0.v, o0);
      o1 = MFMA32(af.v, b1.v, o1);
    }

    if (pf) writeV(cur ^ 1, vt);   // V write after compute (global latency hidden)
    __syncthreads();               // K dma drained (vmcnt0) + V visible; cur reads done
  }

  // ---- epilogue: combine l across halves, normalize, store bf16
  lsum += __shfl(lsum, l ^ 32);
  const float linv = 1.0f / lsum;
  #pragma unroll
  for (int r = 0; r < 16; ++r){
    const int row = (r & 3) + 8*(r >> 2) + 4*(l >> 5);
    const float ivr = __shfl(linv, row | (l & 32));
    const int qg = q0w + row;
    u16* op = aout + (size_t)(b*SEQ + qg) * HIDDEN + h*64 + (l & 31);
    op[0]  = f2bf(o0[r] * ivr);
    op[32] = f2bf(o1[r] * ivr);
  }
}

// ---------------- launch ----------------
extern "C" void kernel_launch(void* const* d_in, const int* in_sizes, int n_in,
                              void* d_out, int out_size, void* d_ws, size_t ws_size,
                              hipStream_t stream){
  const float* enc    = (const float*)d_in[0];
  const float* attn_w = (const float*)d_in[1];
  const float* attn_b = (const float*)d_in[2];
  const float* out_w  = (const float*)d_in[3];
  const float* out_b  = (const float*)d_in[4];

  char* ws = (char*)d_ws;
  u16* enc_bf = (u16*)(ws);
  u16* wa_bf  = (u16*)(ws + (size_t)( 8u << 20));
  u16* wo_bf  = (u16*)(ws + (size_t)(14u << 20));
  u16* qkv    = (u16*)(ws + (size_t)(16u << 20));
  u16* aout   = enc_bf;  // safe alias: attn runs strictly after GEMM1

  k_cvt<<<dim3((MROWS*HIDDEN/4 + 255)/256), 256, 0, stream>>>(enc,    enc_bf, MROWS*HIDDEN/4);
  k_cvt<<<dim3((QKVC*HIDDEN/4  + 255)/256), 256, 0, stream>>>(attn_w, wa_bf,  QKVC*HIDDEN/4);
  k_cvt<<<dim3((HIDDEN*HIDDEN/4+ 255)/256), 256, 0, stream>>>(out_w,  wo_bf,  HIDDEN*HIDDEN/4);

  k_gemm<QKVC,  true ><<<dim3(MROWS/128, QKVC/128),  256, 0, stream>>>(enc_bf, wa_bf, attn_b, qkv);
  k_attn<<<dim3(32, 32), 128, 0, stream>>>(qkv, aout);
  k_gemm<HIDDEN, false><<<dim3(MROWS/128, HIDDEN/128), 256, 0, stream>>>(aout, wo_bf, out_b, d_out);
}

// Round 5
// 148.038 us; speedup vs baseline: 1.0348x; 1.0348x over previous
//
#include <hip/hip_runtime.h>
#include <hip/hip_bf16.h>
#include <stdint.h>

#define HIDDEN 1024
#define NHEADS 16
#define DHEAD  64
#define BATCH  2
#define SEQ    2048
#define MROWS  (BATCH*SEQ)   // 4096
#define QKVC   (3*HIDDEN)    // 3072

typedef unsigned short u16;
typedef unsigned int   u32;
typedef __bf16 bf16x8 __attribute__((ext_vector_type(8)));
typedef __bf16 bf16x2 __attribute__((ext_vector_type(2)));
typedef float  f32x4  __attribute__((ext_vector_type(4)));
typedef float  f32x16 __attribute__((ext_vector_type(16)));
typedef short  s16x4  __attribute__((ext_vector_type(4)));
typedef u16    u16x8  __attribute__((ext_vector_type(8)));
typedef u32    u32x2  __attribute__((ext_vector_type(2)));

typedef const __attribute__((address_space(1))) void gvoid_t;
typedef       __attribute__((address_space(3))) void lvoid_t;

__device__ __forceinline__ gvoid_t* to_glob(const void* p){
  return (gvoid_t*)(uintptr_t)p;
}
__device__ __forceinline__ lvoid_t* to_lds(void* p){
  return (lvoid_t*)(uintptr_t)p;
}
__device__ __forceinline__ u32 lds_off(const void* p){
  return (u32)(uintptr_t)p;
}

// native f32->bf16 (hardware RNE cvt on gfx950; was manual bit-twiddle = ~4 VALU ops)
__device__ __forceinline__ u16 f2bf(float x){
  __bf16 h = (__bf16)x;
  return __builtin_bit_cast(u16, h);
}
// packed f32x2 -> bf16x2 word (compiler emits v_cvt_pk_bf16_f32)
__device__ __forceinline__ u32 pk2(float a, float b){
  bf16x2 t = { (__bf16)a, (__bf16)b };
  return __builtin_bit_cast(u32, t);
}

#define MFMA32(a, b, c) __builtin_amdgcn_mfma_f32_32x32x16_bf16(a, b, c, 0, 0, 0)

// ---------------- fp32 -> bf16 conversion ----------------
__global__ __launch_bounds__(256) void k_cvt(const float* __restrict__ in,
                                             u16* __restrict__ out, int n4){
  int i = blockIdx.x * 256 + threadIdx.x;
  if (i >= n4) return;
  const float4 v = reinterpret_cast<const float4*>(in)[i];
  ushort4 o;
  o.x = f2bf(v.x); o.y = f2bf(v.y); o.z = f2bf(v.z); o.w = f2bf(v.w);
  reinterpret_cast<ushort4*>(out)[i] = o;
}

// ---------------- bf16 GEMM, C = A * B^T + bias (structure unchanged) ----------------
template<int NC, bool BF16OUT>
__global__ __launch_bounds__(256) void k_gemm(const u16* __restrict__ A,
                                              const u16* __restrict__ B,
                                              const float* __restrict__ bias,
                                              void* __restrict__ C){
  constexpr int K = HIDDEN;
  __shared__ u16 As[128*32];
  __shared__ u16 Bs[128*32];
  const int m0 = blockIdx.x * 128;
  const int n0 = blockIdx.y * 128;
  const int tid = threadIdx.x;
  const int w = tid >> 6, l = tid & 63;
  const int wr = w >> 1, wc = w & 1;

  const f32x4 fz = {0.f, 0.f, 0.f, 0.f};
  f32x4 acc[4][4];
  #pragma unroll
  for (int i = 0; i < 4; ++i)
    #pragma unroll
    for (int j = 0; j < 4; ++j) acc[i][j] = fz;

  const u16* ap = A + (size_t)(m0 + (tid >> 2)) * K + (tid & 3) * 8;
  const u16* bp = B + (size_t)(n0 + (tid >> 2)) * K + (tid & 3) * 8;

  for (int k0 = 0; k0 < K; k0 += 32){
    __syncthreads();
    __builtin_amdgcn_global_load_lds(to_glob(ap + k0),          to_lds(&As[w*512]),        16, 0, 0);
    __builtin_amdgcn_global_load_lds(to_glob(ap + 64*K + k0),   to_lds(&As[2048 + w*512]), 16, 0, 0);
    __builtin_amdgcn_global_load_lds(to_glob(bp + k0),          to_lds(&Bs[w*512]),        16, 0, 0);
    __builtin_amdgcn_global_load_lds(to_glob(bp + 64*K + k0),   to_lds(&Bs[2048 + w*512]), 16, 0, 0);
    __syncthreads();

    bf16x8 af[4], bfr[4];
    #pragma unroll
    for (int mf = 0; mf < 4; ++mf)
      af[mf]  = *(const bf16x8*)&As[(wr*64 + mf*16 + (l & 15))*32 + (l >> 4)*8];
    #pragma unroll
    for (int nf = 0; nf < 4; ++nf)
      bfr[nf] = *(const bf16x8*)&Bs[(wc*64 + nf*16 + (l & 15))*32 + (l >> 4)*8];
    #pragma unroll
    for (int mf = 0; mf < 4; ++mf)
      #pragma unroll
      for (int nf = 0; nf < 4; ++nf)
        acc[mf][nf] = __builtin_amdgcn_mfma_f32_16x16x32_bf16(af[mf], bfr[nf], acc[mf][nf], 0, 0, 0);
  }

  #pragma unroll
  for (int nf = 0; nf < 4; ++nf){
    const int col = n0 + wc*64 + nf*16 + (l & 15);
    const float bv = bias[col];
    #pragma unroll
    for (int mf = 0; mf < 4; ++mf){
      #pragma unroll
      for (int r = 0; r < 4; ++r){
        const int row = m0 + wr*64 + mf*16 + (l >> 4)*4 + r;
        const float v = acc[mf][nf][r] + bv;
        if constexpr (BF16OUT) ((u16*)C)[(size_t)row * NC + col] = f2bf(v);
        else                   ((float*)C)[(size_t)row * NC + col] = v;
      }
    }
  }
}

// ---------------- causal flash attention: 32x32 swapped-QK^T, in-register softmax ----
// grid = (32 bh, 32 row-groups), block = 128 (2 waves x 32 q-rows).
// R5: native cvt_pk for P->bf16; permlane32_swap exchange (VALU, no lgkm);
// all 16 tr_reads issued before exp phase so softmax hides their latency.
__global__ __launch_bounds__(128) void k_attn(const u16* __restrict__ qkv,
                                              u16* __restrict__ aout){
  __shared__ u16 Ks[2][64*64];   // [buf][k][d] row 128B, chunk^(row&7) XOR swizzle
  __shared__ u16 Vs[2][64*64];   // [buf] subtiled: elem(k,d) -> (k>>2)*256+(d>>4)*64+(k&3)*16+(d&15)

  const int bh = blockIdx.x;
  const int b  = bh >> 4;
  const int h  = bh & 15;
  const int yy = blockIdx.y;
  const int ii = (yy & 1) ? (31 - (yy >> 1)) : (yy >> 1);   // balance remap
  const int tid = threadIdx.x;
  const int w = tid >> 6, l = tid & 63;
  const int q0w = ii*64 + w*32;                 // this wave's 32 q-rows
  const size_t base = (size_t)b * SEQ * QKVC + (size_t)h * 192;
  const float CEXP = 0.18033688011112042f;      // 0.125 * log2(e)

  // Q B-frags: col=q=(l&31), k-dim=d=(l>>5)*8 + dd*16 + j
  bf16x8 qf[4];
  {
    const u16* qp = qkv + base + (size_t)(q0w + (l & 31)) * QKVC + (l >> 5) * 8;
    #pragma unroll
    for (int dd = 0; dd < 4; ++dd) qf[dd] = *(const bf16x8*)(qp + dd*16);
  }

  f32x16 o0{}, o1{};              // O[q=row(r)][d=(l&31)+{0,32}]
  float m = -1e30f, lsum = 0.f;   // per-lane state for q = l&31 (half k-coverage)

  auto stageK = [&](int kt, int buf){
    #pragma unroll
    for (int t = 0; t < 4; ++t){
      const int i  = t*128 + tid;
      const int kr = i >> 3;
      const int cg = (i & 7) ^ (kr & 7);     // pre-swizzled global source (rule #21)
      const u16* src = qkv + base + (size_t)(kt*64 + kr) * QKVC + 64 + cg * 8;
      __builtin_amdgcn_global_load_lds(to_glob(src), to_lds(&Ks[buf][t*1024 + w*512]), 16, 0, 0);
    }
  };
  auto loadV = [&](int kt, u16x8* vt){
    #pragma unroll
    for (int t = 0; t < 4; ++t){
      const int i = t*128 + tid;
      const int k = i >> 3, d0 = (i & 7) * 8;
      vt[t] = *(const u16x8*)(qkv + base + (size_t)(kt*64 + k) * QKVC + 128 + d0);
    }
  };
  auto writeV = [&](int buf, const u16x8* vt){
    #pragma unroll
    for (int t = 0; t < 4; ++t){
      const int i = t*128 + tid;
      const int k = i >> 3, d0 = (i & 7) * 8;
      const int eo = (k >> 2)*256 + (d0 >> 4)*64 + (k & 3)*16 + (d0 & 15);
      *(u16x8*)&Vs[buf][eo] = vt[t];
    }
  };

  {  // prologue: tile 0 -> buf 0
    u16x8 vt[4];
    stageK(0, 0);
    loadV(0, vt);
    writeV(0, vt);
  }
  __syncthreads();

  const u32 vbase = lds_off(&Vs[0][0]) + (l & 15)*8 + ((l >> 4) & 1)*128 + (l >> 5)*1024;

  for (int kt = 0; kt <= ii; ++kt){
    const int cur = kt & 1;
    const bool pf = (kt < ii);
    u16x8 vt[4];
    if (pf){ stageK(kt + 1, cur ^ 1); loadV(kt + 1, vt); }   // issue early (T14)

    // ---- QK^T: S^T[k][q], acc0 = k 0..31, acc1 = k 32..63
    f32x16 acc0{}, acc1{};
    #pragma unroll
    for (int dd = 0; dd < 4; ++dd){
      const int r0 = l & 31, r1 = 32 + (l & 31);
      const int c  = dd*2 + (l >> 5);
      const bf16x8 k0 = *(const bf16x8*)&Ks[cur][r0*64 + (c ^ (r0 & 7))*8];
      const bf16x8 k1 = *(const bf16x8*)&Ks[cur][r1*64 + (c ^ (r1 & 7))*8];
      acc0 = MFMA32(k0, qf[dd], acc0);
      acc1 = MFMA32(k1, qf[dd], acc1);
    }

    // ---- causal mask (only the final k-tile is diagonal for both waves)
    if (kt == ii){
      const int qg = q0w + (l & 31);
      #pragma unroll
      for (int r = 0; r < 16; ++r){
        const int kg = kt*64 + (r & 3) + 8*(r >> 2) + 4*(l >> 5);
        if (kg      > qg) acc0[r] = -1e30f;
        if (kg + 32 > qg) acc1[r] = -1e30f;
      }
    }

    // ---- row-max (in-lane tree + one cross-half shfl)
    float pm = -1e30f;
    #pragma unroll
    for (int r = 0; r < 16; ++r)
      pm = fmaxf(pm, fmaxf(acc0[r], acc1[r]));
    pm = fmaxf(pm, __shfl(pm, l ^ 32));   // combine k-halves (same q)

    // ---- issue ALL 16 tr_reads now; exp phase below hides the LDS latency
    s16x4 tr[16];
    {
      const u32 vb = vbase + (cur ? 8192u : 0u);
      #pragma unroll
      for (int kk = 0; kk < 4; ++kk){
        asm volatile("ds_read_b64_tr_b16 %0, %4 offset:0\n\t"
                     "ds_read_b64_tr_b16 %1, %4 offset:512\n\t"
                     "ds_read_b64_tr_b16 %2, %4 offset:256\n\t"
                     "ds_read_b64_tr_b16 %3, %4 offset:768"
                     : "=&v"(tr[kk*4+0]), "=&v"(tr[kk*4+1]),
                       "=&v"(tr[kk*4+2]), "=&v"(tr[kk*4+3])
                     : "v"(vb + kk*2048));
      }
    }

    if (__any(pm > m + 64.f)){            // T13 defer-max (THR=64 raw == 8 scaled)
      const float mn = fmaxf(m, pm);
      const float corr = exp2f((m - mn) * CEXP);
      m = mn;
      lsum *= corr;
      #pragma unroll
      for (int r = 0; r < 16; ++r){
        const int row = (r & 3) + 8*(r >> 2) + 4*(l >> 5);
        const float cr = __shfl(corr, row | (l & 32));
        o0[r] *= cr; o1[r] *= cr;
      }
    }
    #pragma unroll
    for (int r = 0; r < 16; ++r){
      const float p0 = exp2f((acc0[r] - m) * CEXP);
      const float p1 = exp2f((acc1[r] - m) * CEXP);
      lsum += p0 + p1;
      acc0[r] = p0; acc1[r] = p1;
    }

    // ---- wait for V once, then PV: A-frag via cvt_pk + permlane32_swap (pure VALU)
    asm volatile("s_waitcnt lgkmcnt(0)" ::: "memory");
    __builtin_amdgcn_sched_barrier(0);
    #pragma unroll
    for (int kk = 0; kk < 4; ++kk){
      const f32x16 A = (kk < 2) ? acc0 : acc1;   // folds: kk is unroll-constant
      const int o = (kk & 1) * 8;
      const u32 x0 = pk2(A[o+0], A[o+1]);
      const u32 x1 = pk2(A[o+2], A[o+3]);
      const u32 y0 = pk2(A[o+4], A[o+5]);
      const u32 y1 = pk2(A[o+6], A[o+7]);
      // swap: r[0] = word for k-sub {0,1}, r[1] = word for k-sub {2,3} (all lanes)
      const u32x2 r0 = __builtin_amdgcn_permlane32_swap(x0, y0, false, false);
      const u32x2 r1 = __builtin_amdgcn_permlane32_swap(x1, y1, false, false);
      union { u32 wd[4]; bf16x8 v; } af;
      af.wd[0] = r0[0]; af.wd[1] = r1[0]; af.wd[2] = r0[1]; af.wd[3] = r1[1];

      union { s16x4 hh[2]; bf16x8 v; } b0, b1;
      b0.hh[0] = tr[kk*4+0]; b0.hh[1] = tr[kk*4+1];
      b1.hh[0] = tr[kk*4+2]; b1.hh[1] = tr[kk*4+3];
      o0 = MFMA32(af.v, b0.v, o0);
      o1 = MFMA32(af.v, b1.v, o1);
    }

    if (pf) writeV(cur ^ 1, vt);   // V write after compute (global latency hidden)
    __syncthreads();               // K dma drained (vmcnt0) + V visible; cur reads done
  }

  // ---- epilogue: combine l across halves, normalize, store bf16
  lsum += __shfl(lsum, l ^ 32);
  const float linv = 1.0f / lsum;
  #pragma unroll
  for (int r = 0; r < 16; ++r){
    const int row = (r & 3) + 8*(r >> 2) + 4*(l >> 5);
    const float ivr = __shfl(linv, row | (l & 32));
    const int qg = q0w + row;
    u16* op = aout + (size_t)(b*SEQ + qg) * HIDDEN + h*64 + (l & 31);
    op[0]  = f2bf(o0[r] * ivr);
    op[32] = f2bf(o1[r] * ivr);
  }
}

// ---------------- launch ----------------
extern "C" void kernel_launch(void* const* d_in, const int* in_sizes, int n_in,
                              void* d_out, int out_size, void* d_ws, size_t ws_size,
                              hipStream_t stream){
  const float* enc    = (const float*)d_in[0];
  const float* attn_w = (const float*)d_in[1];
  const float* attn_b = (const float*)d_in[2];
  const float* out_w  = (const float*)d_in[3];
  const float* out_b  = (const float*)d_in[4];

  char* ws = (char*)d_ws;
  u16* enc_bf = (u16*)(ws);
  u16* wa_bf  = (u16*)(ws + (size_t)( 8u << 20));
  u16* wo_bf  = (u16*)(ws + (size_t)(14u << 20));
  u16* qkv    = (u16*)(ws + (size_t)(16u << 20));
  u16* aout   = enc_bf;  // safe alias: attn runs strictly after GEMM1

  k_cvt<<<dim3((MROWS*HIDDEN/4 + 255)/256), 256, 0, stream>>>(enc,    enc_bf, MROWS*HIDDEN/4);
  k_cvt<<<dim3((QKVC*HIDDEN/4  + 255)/256), 256, 0, stream>>>(attn_w, wa_bf,  QKVC*HIDDEN/4);
  k_cvt<<<dim3((HIDDEN*HIDDEN/4+ 255)/256), 256, 0, stream>>>(out_w,  wo_bf,  HIDDEN*HIDDEN/4);

  k_gemm<QKVC,  true ><<<dim3(MROWS/128, QKVC/128),  256, 0, stream>>>(enc_bf, wa_bf, attn_b, qkv);
  k_attn<<<dim3(32, 32), 128, 0, stream>>>(qkv, aout);
  k_gemm<HIDDEN, false><<<dim3(MROWS/128, HIDDEN/128), 256, 0, stream>>>(aout, wo_bf, out_b, d_out);
}

// Round 6
// 133.101 us; speedup vs baseline: 1.1509x; 1.1122x over previous
//
#include <hip/hip_runtime.h>
#include <hip/hip_bf16.h>
#include <stdint.h>

#define HIDDEN 1024
#define NHEADS 16
#define DHEAD  64
#define BATCH  2
#define SEQ    2048
#define MROWS  (BATCH*SEQ)   // 4096
#define QKVC   (3*HIDDEN)    // 3072

typedef unsigned short u16;
typedef unsigned int   u32;
typedef __bf16 bf16x8 __attribute__((ext_vector_type(8)));
typedef __bf16 bf16x2 __attribute__((ext_vector_type(2)));
typedef float  f32x4  __attribute__((ext_vector_type(4)));
typedef float  f32x16 __attribute__((ext_vector_type(16)));
typedef short  s16x4  __attribute__((ext_vector_type(4)));
typedef u16    u16x8  __attribute__((ext_vector_type(8)));
typedef u32    u32x2  __attribute__((ext_vector_type(2)));

typedef const __attribute__((address_space(1))) void gvoid_t;
typedef       __attribute__((address_space(3))) void lvoid_t;

__device__ __forceinline__ gvoid_t* to_glob(const void* p){
  return (gvoid_t*)(uintptr_t)p;
}
__device__ __forceinline__ lvoid_t* to_lds(void* p){
  return (lvoid_t*)(uintptr_t)p;
}
__device__ __forceinline__ u32 lds_off(const void* p){
  return (u32)(uintptr_t)p;
}

// native f32->bf16 (hardware RNE cvt on gfx950)
__device__ __forceinline__ u16 f2bf(float x){
  __bf16 h = (__bf16)x;
  return __builtin_bit_cast(u16, h);
}
// packed f32x2 -> bf16x2 word (compiler emits v_cvt_pk_bf16_f32)
__device__ __forceinline__ u32 pk2(float a, float b){
  bf16x2 t = { (__bf16)a, (__bf16)b };
  return __builtin_bit_cast(u32, t);
}

#define MFMA32(a, b, c) __builtin_amdgcn_mfma_f32_32x32x16_bf16(a, b, c, 0, 0, 0)

// ---------------- fp32 -> bf16 conversion ----------------
__global__ __launch_bounds__(256) void k_cvt(const float* __restrict__ in,
                                             u16* __restrict__ out, int n4){
  int i = blockIdx.x * 256 + threadIdx.x;
  if (i >= n4) return;
  const float4 v = reinterpret_cast<const float4*>(in)[i];
  ushort4 o;
  o.x = f2bf(v.x); o.y = f2bf(v.y); o.z = f2bf(v.z); o.w = f2bf(v.w);
  reinterpret_cast<ushort4*>(out)[i] = o;
}

// ---------------- bf16 GEMM, C = A * B^T + bias ----------------
// R6: minimum 2-phase prefetch (m248): dbuf LDS, stage(t+1) issued BEFORE
// compute(t), single __syncthreads per K-step -> DMA latency hides under MFMA.
template<int NC, bool BF16OUT>
__global__ __launch_bounds__(256) void k_gemm(const u16* __restrict__ A,
                                              const u16* __restrict__ B,
                                              const float* __restrict__ bias,
                                              void* __restrict__ C){
  constexpr int K = HIDDEN;
  __shared__ u16 As[2][128*32];
  __shared__ u16 Bs[2][128*32];
  const int m0 = blockIdx.x * 128;
  const int n0 = blockIdx.y * 128;
  const int tid = threadIdx.x;
  const int w = tid >> 6, l = tid & 63;
  const int wr = w >> 1, wc = w & 1;

  const f32x4 fz = {0.f, 0.f, 0.f, 0.f};
  f32x4 acc[4][4];
  #pragma unroll
  for (int i = 0; i < 4; ++i)
    #pragma unroll
    for (int j = 0; j < 4; ++j) acc[i][j] = fz;

  const u16* ap = A + (size_t)(m0 + (tid >> 2)) * K + (tid & 3) * 8;
  const u16* bp = B + (size_t)(n0 + (tid >> 2)) * K + (tid & 3) * 8;

  auto stage = [&](int k0, int buf){
    __builtin_amdgcn_global_load_lds(to_glob(ap + k0),        to_lds(&As[buf][w*512]),        16, 0, 0);
    __builtin_amdgcn_global_load_lds(to_glob(ap + 64*K + k0), to_lds(&As[buf][2048 + w*512]), 16, 0, 0);
    __builtin_amdgcn_global_load_lds(to_glob(bp + k0),        to_lds(&Bs[buf][w*512]),        16, 0, 0);
    __builtin_amdgcn_global_load_lds(to_glob(bp + 64*K + k0), to_lds(&Bs[buf][2048 + w*512]), 16, 0, 0);
  };

  stage(0, 0);
  __syncthreads();                       // vmcnt(0) + barrier: buf0 ready

  for (int k0 = 0; k0 < K; k0 += 32){
    const int cur = (k0 >> 5) & 1;
    if (k0 + 32 < K) stage(k0 + 32, cur ^ 1);   // prefetch overlaps compute below

    bf16x8 af[4], bfr[4];
    #pragma unroll
    for (int mf = 0; mf < 4; ++mf)
      af[mf]  = *(const bf16x8*)&As[cur][(wr*64 + mf*16 + (l & 15))*32 + (l >> 4)*8];
    #pragma unroll
    for (int nf = 0; nf < 4; ++nf)
      bfr[nf] = *(const bf16x8*)&Bs[cur][(wc*64 + nf*16 + (l & 15))*32 + (l >> 4)*8];
    #pragma unroll
    for (int mf = 0; mf < 4; ++mf)
      #pragma unroll
      for (int nf = 0; nf < 4; ++nf)
        acc[mf][nf] = __builtin_amdgcn_mfma_f32_16x16x32_bf16(af[mf], bfr[nf], acc[mf][nf], 0, 0, 0);

    __syncthreads();   // drains prefetch DMA (now covered) + protects buf reuse
  }

  #pragma unroll
  for (int nf = 0; nf < 4; ++nf){
    const int col = n0 + wc*64 + nf*16 + (l & 15);
    const float bv = bias[col];
    #pragma unroll
    for (int mf = 0; mf < 4; ++mf){
      #pragma unroll
      for (int r = 0; r < 4; ++r){
        const int row = m0 + wr*64 + mf*16 + (l >> 4)*4 + r;
        const float v = acc[mf][nf][r] + bv;
        if constexpr (BF16OUT) ((u16*)C)[(size_t)row * NC + col] = f2bf(v);
        else                   ((float*)C)[(size_t)row * NC + col] = v;
      }
    }
  }
}

// ---------------- causal flash attention: paired q-tiles, 32x32 swapped-QK^T ----
// grid = (32 bh, 16 pairs), block = 128 (2 waves). Block owns q-tiles
// {A=p, B=31-p}: constant 33 tile-units per block -> balanced makespan (fixes
// R5's 8% occupancy tail). Dual iterations (kt<=A) run BOTH streams off one
// staged K/V tile: staging/kf/tr_reads amortized 2x, B-stream hides A latency.
__global__ __launch_bounds__(128) void k_attn(const u16* __restrict__ qkv,
                                              u16* __restrict__ aout){
  __shared__ u16 Ks[2][64*64];   // [buf][k][d], chunk^(row&7) XOR swizzle
  __shared__ u16 Vs[2][64*64];   // [buf] subtiled for ds_read_b64_tr_b16

  const int bh = blockIdx.x;
  const int b  = bh >> 4;
  const int h  = bh & 15;
  const int p  = blockIdx.y;        // 0..15
  const int Aq = p, Bq = 31 - p;    // paired q-tiles
  const int tid = threadIdx.x;
  const int w = tid >> 6, l = tid & 63;
  const int qA0 = Aq*64 + w*32;     // this wave's 32 q-rows, stream A
  const int qB0 = Bq*64 + w*32;     // stream B
  const size_t base = (size_t)b * SEQ * QKVC + (size_t)h * 192;
  const float CEXP = 0.18033688011112042f;      // 0.125 * log2(e)

  // Q B-frags: col=q=(l&31), k-dim=d=(l>>5)*8 + dd*16 + j
  bf16x8 qfA[4], qfB[4];
  {
    const u16* qa = qkv + base + (size_t)(qA0 + (l & 31)) * QKVC + (l >> 5) * 8;
    const u16* qb = qkv + base + (size_t)(qB0 + (l & 31)) * QKVC + (l >> 5) * 8;
    #pragma unroll
    for (int dd = 0; dd < 4; ++dd){
      qfA[dd] = *(const bf16x8*)(qa + dd*16);
      qfB[dd] = *(const bf16x8*)(qb + dd*16);
    }
  }

  f32x16 oA0{}, oA1{}, oB0{}, oB1{};
  float mA = -1e30f, lsA = 0.f, mB = -1e30f, lsB = 0.f;

  auto stageK = [&](int kt, int buf){
    #pragma unroll
    for (int t = 0; t < 4; ++t){
      const int i  = t*128 + tid;
      const int kr = i >> 3;
      const int cg = (i & 7) ^ (kr & 7);     // pre-swizzled global source
      const u16* src = qkv + base + (size_t)(kt*64 + kr) * QKVC + 64 + cg * 8;
      __builtin_amdgcn_global_load_lds(to_glob(src), to_lds(&Ks[buf][t*1024 + w*512]), 16, 0, 0);
    }
  };
  auto loadV = [&](int kt, u16x8* vt){
    #pragma unroll
    for (int t = 0; t < 4; ++t){
      const int i = t*128 + tid;
      const int k = i >> 3, d0 = (i & 7) * 8;
      vt[t] = *(const u16x8*)(qkv + base + (size_t)(kt*64 + k) * QKVC + 128 + d0);
    }
  };
  auto writeV = [&](int buf, const u16x8* vt){
    #pragma unroll
    for (int t = 0; t < 4; ++t){
      const int i = t*128 + tid;
      const int k = i >> 3, d0 = (i & 7) * 8;
      const int eo = (k >> 2)*256 + (d0 >> 4)*64 + (k & 3)*16 + (d0 & 15);
      *(u16x8*)&Vs[buf][eo] = vt[t];
    }
  };

  // softmax: mask(optional) + row-max + defer-max rescale + exp; acc -> P
  auto softmax = [&](f32x16& a0, f32x16& a1, float& m, float& ls,
                     f32x16& o0, f32x16& o1, bool diag, int q0s, int kt){
    if (diag){
      const int qg = q0s + (l & 31);
      #pragma unroll
      for (int r = 0; r < 16; ++r){
        const int kg = kt*64 + (r & 3) + 8*(r >> 2) + 4*(l >> 5);
        if (kg      > qg) a0[r] = -1e30f;
        if (kg + 32 > qg) a1[r] = -1e30f;
      }
    }
    float pm = -1e30f;
    #pragma unroll
    for (int r = 0; r < 16; ++r)
      pm = fmaxf(pm, fmaxf(a0[r], a1[r]));
    pm = fmaxf(pm, __shfl(pm, l ^ 32));   // combine k-halves (same q)

    if (__any(pm > m + 64.f)){            // T13 defer-max
      const float mn = fmaxf(m, pm);
      const float corr = exp2f((m - mn) * CEXP);
      m = mn;
      ls *= corr;
      #pragma unroll
      for (int r = 0; r < 16; ++r){
        const int row = (r & 3) + 8*(r >> 2) + 4*(l >> 5);
        const float cr = __shfl(corr, row | (l & 32));
        o0[r] *= cr; o1[r] *= cr;
      }
    }
    float s0 = 0.f, s1 = 0.f;
    #pragma unroll
    for (int r = 0; r < 16; ++r){
      const float p0 = exp2f((a0[r] - m) * CEXP);
      const float p1 = exp2f((a1[r] - m) * CEXP);
      s0 += p0; s1 += p1;
      a0[r] = p0; a1[r] = p1;
    }
    ls += s0 + s1;
  };

  // PV: A-frag from P via cvt_pk + permlane32_swap; B-frags from tr regs
  auto pv = [&](const f32x16& a0, const f32x16& a1,
                f32x16& o0, f32x16& o1, const s16x4* tr){
    #pragma unroll
    for (int kk = 0; kk < 4; ++kk){
      const f32x16& Ac = (kk < 2) ? a0 : a1;
      const int o = (kk & 1) * 8;
      const u32 x0 = pk2(Ac[o+0], Ac[o+1]);
      const u32 x1 = pk2(Ac[o+2], Ac[o+3]);
      const u32 y0 = pk2(Ac[o+4], Ac[o+5]);
      const u32 y1 = pk2(Ac[o+6], Ac[o+7]);
      const u32x2 r0 = __builtin_amdgcn_permlane32_swap(x0, y0, false, false);
      const u32x2 r1 = __builtin_amdgcn_permlane32_swap(x1, y1, false, false);
      union { u32 wd[4]; bf16x8 v; } af;
      af.wd[0] = r0[0]; af.wd[1] = r1[0]; af.wd[2] = r0[1]; af.wd[3] = r1[1];
      union { s16x4 hh[2]; bf16x8 v; } b0, b1;
      b0.hh[0] = tr[kk*4+0]; b0.hh[1] = tr[kk*4+1];
      b1.hh[0] = tr[kk*4+2]; b1.hh[1] = tr[kk*4+3];
      o0 = MFMA32(af.v, b0.v, o0);
      o1 = MFMA32(af.v, b1.v, o1);
    }
  };

  {  // prologue: tile 0 -> buf 0
    u16x8 vt[4];
    stageK(0, 0);
    loadV(0, vt);
    writeV(0, vt);
  }
  __syncthreads();

  const u32 vbase = lds_off(&Vs[0][0]) + (l & 15)*8 + ((l >> 4) & 1)*128 + (l >> 5)*1024;

  for (int kt = 0; kt <= Bq; ++kt){
    const int cur = kt & 1;
    const bool pf   = (kt < Bq);
    const bool dual = (kt <= Aq);
    u16x8 vt[4];
    if (pf){ loadV(kt + 1, vt); stageK(kt + 1, cur ^ 1); }   // issue early (T14)

    // ---- QK^T stream B (always) and A (dual): S^T[k][q]
    f32x16 aB0{}, aB1{}, aA0{}, aA1{};
    #pragma unroll
    for (int dd = 0; dd < 4; ++dd){
      const int r0 = l & 31, r1 = 32 + (l & 31);
      const int c  = dd*2 + (l >> 5);
      const bf16x8 k0 = *(const bf16x8*)&Ks[cur][r0*64 + (c ^ (r0 & 7))*8];
      const bf16x8 k1 = *(const bf16x8*)&Ks[cur][r1*64 + (c ^ (r1 & 7))*8];
      aB0 = MFMA32(k0, qfB[dd], aB0);
      aB1 = MFMA32(k1, qfB[dd], aB1);
    }
    if (dual){
      #pragma unroll
      for (int dd = 0; dd < 4; ++dd){
        const int r0 = l & 31, r1 = 32 + (l & 31);
        const int c  = dd*2 + (l >> 5);
        const bf16x8 k0 = *(const bf16x8*)&Ks[cur][r0*64 + (c ^ (r0 & 7))*8];
        const bf16x8 k1 = *(const bf16x8*)&Ks[cur][r1*64 + (c ^ (r1 & 7))*8];
        aA0 = MFMA32(k0, qfA[dd], aA0);
        aA1 = MFMA32(k1, qfA[dd], aA1);
      }
    }

    // ---- issue ALL 16 tr_reads now; softmax below hides the LDS latency.
    // (All compiler ds_reads above are consumed by the MFMAs; no compiler
    //  ds-op issues between here and the explicit lgkmcnt(0).)
    s16x4 tr[16];
    {
      const u32 vb = vbase + (cur ? 8192u : 0u);
      #pragma unroll
      for (int kk = 0; kk < 4; ++kk){
        asm volatile("ds_read_b64_tr_b16 %0, %4 offset:0\n\t"
                     "ds_read_b64_tr_b16 %1, %4 offset:512\n\t"
                     "ds_read_b64_tr_b16 %2, %4 offset:256\n\t"
                     "ds_read_b64_tr_b16 %3, %4 offset:768"
                     : "=&v"(tr[kk*4+0]), "=&v"(tr[kk*4+1]),
                       "=&v"(tr[kk*4+2]), "=&v"(tr[kk*4+3])
                     : "v"(vb + kk*2048));
      }
    }

    // ---- softmax (pure VALU/trans; overlaps tr latency)
    softmax(aB0, aB1, mB, lsB, oB0, oB1, kt == Bq, qB0, kt);
    if (dual) softmax(aA0, aA1, mA, lsA, oA0, oA1, kt == Aq, qA0, kt);

    // ---- wait for V once, then PV for both streams off shared tr regs
    asm volatile("s_waitcnt lgkmcnt(0)" ::: "memory");
    __builtin_amdgcn_sched_barrier(0);
    pv(aB0, aB1, oB0, oB1, tr);
    if (dual) pv(aA0, aA1, oA0, oA1, tr);

    if (pf) writeV(cur ^ 1, vt);   // V write after compute (global latency hidden)
    __syncthreads();               // K dma drained + V visible; cur reads done
  }

  // ---- epilogue: combine l across halves, normalize, store bf16
  auto epi = [&](f32x16& o0, f32x16& o1, float ls, int q0s){
    ls += __shfl(ls, l ^ 32);
    const float linv = 1.0f / ls;
    #pragma unroll
    for (int r = 0; r < 16; ++r){
      const int row = (r & 3) + 8*(r >> 2) + 4*(l >> 5);
      const float ivr = __shfl(linv, row | (l & 32));
      const int qg = q0s + row;
      u16* op = aout + (size_t)(b*SEQ + qg) * HIDDEN + h*64 + (l & 31);
      op[0]  = f2bf(o0[r] * ivr);
      op[32] = f2bf(o1[r] * ivr);
    }
  };
  epi(oA0, oA1, lsA, qA0);
  epi(oB0, oB1, lsB, qB0);
}

// ---------------- launch ----------------
extern "C" void kernel_launch(void* const* d_in, const int* in_sizes, int n_in,
                              void* d_out, int out_size, void* d_ws, size_t ws_size,
                              hipStream_t stream){
  const float* enc    = (const float*)d_in[0];
  const float* attn_w = (const float*)d_in[1];
  const float* attn_b = (const float*)d_in[2];
  const float* out_w  = (const float*)d_in[3];
  const float* out_b  = (const float*)d_in[4];

  char* ws = (char*)d_ws;
  u16* enc_bf = (u16*)(ws);
  u16* wa_bf  = (u16*)(ws + (size_t)( 8u << 20));
  u16* wo_bf  = (u16*)(ws + (size_t)(14u << 20));
  u16* qkv    = (u16*)(ws + (size_t)(16u << 20));
  u16* aout   = enc_bf;  // safe alias: attn runs strictly after GEMM1

  k_cvt<<<dim3((MROWS*HIDDEN/4 + 255)/256), 256, 0, stream>>>(enc,    enc_bf, MROWS*HIDDEN/4);
  k_cvt<<<dim3((QKVC*HIDDEN/4  + 255)/256), 256, 0, stream>>>(attn_w, wa_bf,  QKVC*HIDDEN/4);
  k_cvt<<<dim3((HIDDEN*HIDDEN/4+ 255)/256), 256, 0, stream>>>(out_w,  wo_bf,  HIDDEN*HIDDEN/4);

  k_gemm<QKVC,  true ><<<dim3(MROWS/128, QKVC/128),  256, 0, stream>>>(enc_bf, wa_bf, attn_b, qkv);
  k_attn<<<dim3(32, 16), 128, 0, stream>>>(qkv, aout);
  k_gemm<HIDDEN, false><<<dim3(MROWS/128, HIDDEN/128), 256, 0, stream>>>(aout, wo_bf, out_b, d_out);
}

// Round 7
// 125.902 us; speedup vs baseline: 1.2168x; 1.0572x over previous
//
#include <hip/hip_runtime.h>
#include <hip/hip_bf16.h>
#include <stdint.h>

#define HIDDEN 1024
#define NHEADS 16
#define DHEAD  64
#define BATCH  2
#define SEQ    2048
#define MROWS  (BATCH*SEQ)   // 4096
#define QKVC   (3*HIDDEN)    // 3072

typedef unsigned short u16;
typedef unsigned int   u32;
typedef __bf16 bf16x8 __attribute__((ext_vector_type(8)));
typedef __bf16 bf16x2 __attribute__((ext_vector_type(2)));
typedef float  f32x4  __attribute__((ext_vector_type(4)));
typedef float  f32x16 __attribute__((ext_vector_type(16)));
typedef short  s16x4  __attribute__((ext_vector_type(4)));
typedef u16    u16x8  __attribute__((ext_vector_type(8)));
typedef u32    u32x2  __attribute__((ext_vector_type(2)));

typedef const __attribute__((address_space(1))) void gvoid_t;
typedef       __attribute__((address_space(3))) void lvoid_t;

__device__ __forceinline__ gvoid_t* to_glob(const void* p){
  return (gvoid_t*)(uintptr_t)p;
}
__device__ __forceinline__ lvoid_t* to_lds(void* p){
  return (lvoid_t*)(uintptr_t)p;
}
__device__ __forceinline__ u32 lds_off(const void* p){
  return (u32)(uintptr_t)p;
}

// native f32->bf16 (hardware RNE cvt on gfx950)
__device__ __forceinline__ u16 f2bf(float x){
  __bf16 h = (__bf16)x;
  return __builtin_bit_cast(u16, h);
}
// packed f32x2 -> bf16x2 word (compiler emits v_cvt_pk_bf16_f32)
__device__ __forceinline__ u32 pk2(float a, float b){
  bf16x2 t = { (__bf16)a, (__bf16)b };
  return __builtin_bit_cast(u32, t);
}

#define MFMA32(a, b, c) __builtin_amdgcn_mfma_f32_32x32x16_bf16(a, b, c, 0, 0, 0)

// ---------------- fp32 -> bf16 conversion ----------------
__global__ __launch_bounds__(256) void k_cvt(const float* __restrict__ in,
                                             u16* __restrict__ out, int n4){
  int i = blockIdx.x * 256 + threadIdx.x;
  if (i >= n4) return;
  const float4 v = reinterpret_cast<const float4*>(in)[i];
  ushort4 o;
  o.x = f2bf(v.x); o.y = f2bf(v.y); o.z = f2bf(v.z); o.w = f2bf(v.w);
  reinterpret_cast<ushort4*>(out)[i] = o;
}

// ---------------- bf16 GEMM, C = A * B^T + bias (unchanged from R6) ----------------
template<int NC, bool BF16OUT>
__global__ __launch_bounds__(256) void k_gemm(const u16* __restrict__ A,
                                              const u16* __restrict__ B,
                                              const float* __restrict__ bias,
                                              void* __restrict__ C){
  constexpr int K = HIDDEN;
  __shared__ u16 As[2][128*32];
  __shared__ u16 Bs[2][128*32];
  const int m0 = blockIdx.x * 128;
  const int n0 = blockIdx.y * 128;
  const int tid = threadIdx.x;
  const int w = tid >> 6, l = tid & 63;
  const int wr = w >> 1, wc = w & 1;

  const f32x4 fz = {0.f, 0.f, 0.f, 0.f};
  f32x4 acc[4][4];
  #pragma unroll
  for (int i = 0; i < 4; ++i)
    #pragma unroll
    for (int j = 0; j < 4; ++j) acc[i][j] = fz;

  const u16* ap = A + (size_t)(m0 + (tid >> 2)) * K + (tid & 3) * 8;
  const u16* bp = B + (size_t)(n0 + (tid >> 2)) * K + (tid & 3) * 8;

  auto stage = [&](int k0, int buf){
    __builtin_amdgcn_global_load_lds(to_glob(ap + k0),        to_lds(&As[buf][w*512]),        16, 0, 0);
    __builtin_amdgcn_global_load_lds(to_glob(ap + 64*K + k0), to_lds(&As[buf][2048 + w*512]), 16, 0, 0);
    __builtin_amdgcn_global_load_lds(to_glob(bp + k0),        to_lds(&Bs[buf][w*512]),        16, 0, 0);
    __builtin_amdgcn_global_load_lds(to_glob(bp + 64*K + k0), to_lds(&Bs[buf][2048 + w*512]), 16, 0, 0);
  };

  stage(0, 0);
  __syncthreads();

  for (int k0 = 0; k0 < K; k0 += 32){
    const int cur = (k0 >> 5) & 1;
    if (k0 + 32 < K) stage(k0 + 32, cur ^ 1);

    bf16x8 af[4], bfr[4];
    #pragma unroll
    for (int mf = 0; mf < 4; ++mf)
      af[mf]  = *(const bf16x8*)&As[cur][(wr*64 + mf*16 + (l & 15))*32 + (l >> 4)*8];
    #pragma unroll
    for (int nf = 0; nf < 4; ++nf)
      bfr[nf] = *(const bf16x8*)&Bs[cur][(wc*64 + nf*16 + (l & 15))*32 + (l >> 4)*8];
    #pragma unroll
    for (int mf = 0; mf < 4; ++mf)
      #pragma unroll
      for (int nf = 0; nf < 4; ++nf)
        acc[mf][nf] = __builtin_amdgcn_mfma_f32_16x16x32_bf16(af[mf], bfr[nf], acc[mf][nf], 0, 0, 0);

    __syncthreads();
  }

  #pragma unroll
  for (int nf = 0; nf < 4; ++nf){
    const int col = n0 + wc*64 + nf*16 + (l & 15);
    const float bv = bias[col];
    #pragma unroll
    for (int mf = 0; mf < 4; ++mf){
      #pragma unroll
      for (int r = 0; r < 4; ++r){
        const int row = m0 + wr*64 + mf*16 + (l >> 4)*4 + r;
        const float v = acc[mf][nf][r] + bv;
        if constexpr (BF16OUT) ((u16*)C)[(size_t)row * NC + col] = f2bf(v);
        else                   ((float*)C)[(size_t)row * NC + col] = v;
      }
    }
  }
}

// ---------------- causal flash attention: in-block split-K, 32x32 swapped-QK^T ----
// grid = (32 bh, 32 qt, LPT desc), block = 256 (4 waves). One 64-row q-tile per
// block; waves {0,1} = k-tiles [0,nk/2), waves {2,3} = [nk/2,nk) (own LDS region
// each) -> 2048+ concurrent waves (2/SIMD, fixes R6's 1-wave/SIMD latency wall).
// 1024 blocks, 512 resident -> refill + LPT kills the tail. Final (m,l,O) merge
// across halves via LDS (once per block).
__global__ __launch_bounds__(256) void k_attn(const u16* __restrict__ qkv,
                                              u16* __restrict__ aout){
  __shared__ u16 smem[2*16384];   // 64 KiB: per half: K dbuf 2x8KB | V dbuf 2x8KB

  const int bh = blockIdx.x;
  const int b  = bh >> 4;
  const int h  = bh & 15;
  const int qt = 31 - blockIdx.y;          // LPT: longest blocks first
  const int tid = threadIdx.x;
  const int l  = tid & 63;
  const int w  = tid >> 6;
  const int hr = w >> 1;                   // k-half (0 or 1)
  const int wr = w & 1;                    // q-row half within tile
  const int t128 = tid & 127;
  const int lw = t128 >> 6;                // wave-within-half
  const int nk = qt + 1;
  const int n0 = nk >> 1;
  const int myn = hr ? (nk - n0) : n0;     // my half's k-tile count
  const int kb  = hr ? n0 : 0;             // my first k-tile
  const int trips = nk - n0;               // uniform loop count (= max(n0, nk-n0))
  const int q0 = qt*64 + wr*32;            // this wave's 32 q-rows
  const size_t base = (size_t)b * SEQ * QKVC + (size_t)h * 192;
  const float CEXP = 0.18033688011112042f; // 0.125 * log2(e)

  u16* const Kreg = smem + hr*16384;          // + cur*4096 (u16)
  u16* const Vreg = smem + hr*16384 + 8192;   // + cur*4096 (u16)

  // Q B-frags: col=q=(l&31), k-dim=d=(l>>5)*8 + dd*16 + j
  bf16x8 qf[4];
  {
    const u16* qp = qkv + base + (size_t)(q0 + (l & 31)) * QKVC + (l >> 5) * 8;
    #pragma unroll
    for (int dd = 0; dd < 4; ++dd) qf[dd] = *(const bf16x8*)(qp + dd*16);
  }

  f32x16 o0{}, o1{};              // O[q=row(r)][d=(l&31)+{0,32}]
  float m = -1e30f, lsum = 0.f;   // per-lane (q = l&31, own k-rows)

  auto stageK = [&](int kt, int cb){
    #pragma unroll
    for (int t = 0; t < 4; ++t){
      const int i  = t*128 + t128;
      const int kr = i >> 3;
      const int cg = (i & 7) ^ (kr & 7);   // pre-swizzled global source
      const u16* src = qkv + base + (size_t)(kt*64 + kr) * QKVC + 64 + cg * 8;
      __builtin_amdgcn_global_load_lds(to_glob(src), to_lds(&Kreg[cb*4096 + t*1024 + lw*512]), 16, 0, 0);
    }
  };
  auto loadV = [&](int kt, u16x8* vt){
    #pragma unroll
    for (int t = 0; t < 4; ++t){
      const int i = t*128 + t128;
      const int k = i >> 3, d0 = (i & 7) * 8;
      vt[t] = *(const u16x8*)(qkv + base + (size_t)(kt*64 + k) * QKVC + 128 + d0);
    }
  };
  auto writeV = [&](int cb, const u16x8* vt){
    #pragma unroll
    for (int t = 0; t < 4; ++t){
      const int i = t*128 + t128;
      const int k = i >> 3, d0 = (i & 7) * 8;
      const int eo = (k >> 2)*256 + (d0 >> 4)*64 + (k & 3)*16 + (d0 & 15);
      *(u16x8*)&Vreg[cb*4096 + eo] = vt[t];
    }
  };

  if (myn > 0){   // prologue: my first tile -> buf 0
    u16x8 vt[4];
    stageK(kb, 0);
    loadV(kb, vt);
    writeV(0, vt);
  }
  __syncthreads();

  const u32 vbase = lds_off(Vreg) + (l & 15)*8 + ((l >> 4) & 1)*128 + (l >> 5)*1024;

  for (int it = 0; it < trips; ++it){
    const int cur = it & 1;
    const bool act = (it < myn);
    const bool pf  = (it + 1 < myn);
    u16x8 vt[4];
    if (pf){ loadV(kb + it + 1, vt); stageK(kb + it + 1, cur ^ 1); }  // issue early

    if (act){
      const int kt = kb + it;
      // ---- QK^T: S^T[k][q], a0 = k 0..31, a1 = k 32..63 (of this tile)
      f32x16 a0{}, a1{};
      #pragma unroll
      for (int dd = 0; dd < 4; ++dd){
        const int r0 = l & 31, r1 = 32 + (l & 31);
        const int c  = dd*2 + (l >> 5);
        const bf16x8 k0 = *(const bf16x8*)&Kreg[cur*4096 + r0*64 + (c ^ (r0 & 7))*8];
        const bf16x8 k1 = *(const bf16x8*)&Kreg[cur*4096 + r1*64 + (c ^ (r1 & 7))*8];
        a0 = MFMA32(k0, qf[dd], a0);
        a1 = MFMA32(k1, qf[dd], a1);
      }

      // ---- causal mask: only half-1's last tile is diagonal
      if (hr == 1 && it == myn - 1){
        const int qg = q0 + (l & 31);
        #pragma unroll
        for (int r = 0; r < 16; ++r){
          const int kg = kt*64 + (r & 3) + 8*(r >> 2) + 4*(l >> 5);
          if (kg      > qg) a0[r] = -1e30f;
          if (kg + 32 > qg) a1[r] = -1e30f;
        }
      }

      // ---- row-max
      float pm = -1e30f;
      #pragma unroll
      for (int r = 0; r < 16; ++r)
        pm = fmaxf(pm, fmaxf(a0[r], a1[r]));
      pm = fmaxf(pm, __shfl(pm, l ^ 32));

      // ---- issue ALL 16 tr_reads; softmax below hides LDS latency
      s16x4 tr[16];
      {
        const u32 vb = vbase + (cur ? 8192u : 0u);
        #pragma unroll
        for (int kk = 0; kk < 4; ++kk){
          asm volatile("ds_read_b64_tr_b16 %0, %4 offset:0\n\t"
                       "ds_read_b64_tr_b16 %1, %4 offset:512\n\t"
                       "ds_read_b64_tr_b16 %2, %4 offset:256\n\t"
                       "ds_read_b64_tr_b16 %3, %4 offset:768"
                       : "=&v"(tr[kk*4+0]), "=&v"(tr[kk*4+1]),
                         "=&v"(tr[kk*4+2]), "=&v"(tr[kk*4+3])
                       : "v"(vb + kk*2048));
        }
      }

      if (__any(pm > m + 64.f)){            // T13 defer-max
        const float mn = fmaxf(m, pm);
        const float corr = exp2f((m - mn) * CEXP);
        m = mn;
        lsum *= corr;
        #pragma unroll
        for (int r = 0; r < 16; ++r){
          const int row = (r & 3) + 8*(r >> 2) + 4*(l >> 5);
          const float cr = __shfl(corr, row | (l & 32));
          o0[r] *= cr; o1[r] *= cr;
        }
      }
      #pragma unroll
      for (int r = 0; r < 16; ++r){
        const float p0 = exp2f((a0[r] - m) * CEXP);
        const float p1 = exp2f((a1[r] - m) * CEXP);
        lsum += p0 + p1;
        a0[r] = p0; a1[r] = p1;
      }

      // ---- wait V once, then PV: A-frag via cvt_pk + permlane32_swap
      asm volatile("s_waitcnt lgkmcnt(0)" ::: "memory");
      __builtin_amdgcn_sched_barrier(0);
      #pragma unroll
      for (int kk = 0; kk < 4; ++kk){
        const f32x16& Ac = (kk < 2) ? a0 : a1;
        const int o = (kk & 1) * 8;
        const u32 x0 = pk2(Ac[o+0], Ac[o+1]);
        const u32 x1 = pk2(Ac[o+2], Ac[o+3]);
        const u32 y0 = pk2(Ac[o+4], Ac[o+5]);
        const u32 y1 = pk2(Ac[o+6], Ac[o+7]);
        const u32x2 r0 = __builtin_amdgcn_permlane32_swap(x0, y0, false, false);
        const u32x2 r1 = __builtin_amdgcn_permlane32_swap(x1, y1, false, false);
        union { u32 wd[4]; bf16x8 v; } af;
        af.wd[0] = r0[0]; af.wd[1] = r1[0]; af.wd[2] = r0[1]; af.wd[3] = r1[1];
        union { s16x4 hh[2]; bf16x8 v; } b0, b1;
        b0.hh[0] = tr[kk*4+0]; b0.hh[1] = tr[kk*4+1];
        b1.hh[0] = tr[kk*4+2]; b1.hh[1] = tr[kk*4+3];
        o0 = MFMA32(af.v, b0.v, o0);
        o1 = MFMA32(af.v, b1.v, o1);
      }
    }

    if (pf) writeV(cur ^ 1, vt);
    __syncthreads();
  }

  // ---- cross-half merge (once): staging LDS is dead, reuse it
  lsum += __shfl(lsum, l ^ 32);             // combine lane k-halves (same q)
  float* const Osh  = (float*)smem;                         // 16 KB
  float2* const MLsh = (float2*)((char*)smem + 16384);      // 1 KB

  if (hr == 1){
    #pragma unroll
    for (int r = 0; r < 16; ++r){
      Osh[wr*2048 + l*32 + r]      = o0[r];
      Osh[wr*2048 + l*32 + 16 + r] = o1[r];
    }
    MLsh[wr*64 + l] = float2{m, lsum};
  }
  __syncthreads();

  if (hr == 0){
    const float2 ml1 = MLsh[wr*64 + l];
    const float mm = fmaxf(m, ml1.x);
    const float c0 = exp2f((m - mm) * CEXP);
    const float c1 = exp2f((ml1.x - mm) * CEXP);
    const float lm = lsum*c0 + ml1.y*c1;    // >0 always (half-1 non-empty)
    const float a0q = c0 / lm;
    const float a1q = c1 / lm;
    #pragma unroll
    for (int r = 0; r < 16; ++r){
      const int row = (r & 3) + 8*(r >> 2) + 4*(l >> 5);
      const float f0 = __shfl(a0q, row | (l & 32));
      const float f1 = __shfl(a1q, row | (l & 32));
      const int qg = q0 + row;
      u16* op = aout + (size_t)(b*SEQ + qg) * HIDDEN + h*64 + (l & 31);
      op[0]  = f2bf(o0[r]*f0 + Osh[wr*2048 + l*32 + r]*f1);
      op[32] = f2bf(o1[r]*f0 + Osh[wr*2048 + l*32 + 16 + r]*f1);
    }
  }
}

// ---------------- launch ----------------
extern "C" void kernel_launch(void* const* d_in, const int* in_sizes, int n_in,
                              void* d_out, int out_size, void* d_ws, size_t ws_size,
                              hipStream_t stream){
  const float* enc    = (const float*)d_in[0];
  const float* attn_w = (const float*)d_in[1];
  const float* attn_b = (const float*)d_in[2];
  const float* out_w  = (const float*)d_in[3];
  const float* out_b  = (const float*)d_in[4];

  char* ws = (char*)d_ws;
  u16* enc_bf = (u16*)(ws);
  u16* wa_bf  = (u16*)(ws + (size_t)( 8u << 20));
  u16* wo_bf  = (u16*)(ws + (size_t)(14u << 20));
  u16* qkv    = (u16*)(ws + (size_t)(16u << 20));
  u16* aout   = enc_bf;  // safe alias: attn runs strictly after GEMM1

  k_cvt<<<dim3((MROWS*HIDDEN/4 + 255)/256), 256, 0, stream>>>(enc,    enc_bf, MROWS*HIDDEN/4);
  k_cvt<<<dim3((QKVC*HIDDEN/4  + 255)/256), 256, 0, stream>>>(attn_w, wa_bf,  QKVC*HIDDEN/4);
  k_cvt<<<dim3((HIDDEN*HIDDEN/4+ 255)/256), 256, 0, stream>>>(out_w,  wo_bf,  HIDDEN*HIDDEN/4);

  k_gemm<QKVC,  true ><<<dim3(MROWS/128, QKVC/128),  256, 0, stream>>>(enc_bf, wa_bf, attn_b, qkv);
  k_attn<<<dim3(32, 32), 256, 0, stream>>>(qkv, aout);
  k_gemm<HIDDEN, false><<<dim3(MROWS/128, HIDDEN/128), 256, 0, stream>>>(aout, wo_bf, out_b, d_out);
}

// Round 8
// 111.093 us; speedup vs baseline: 1.3790x; 1.1333x over previous
//
#include <hip/hip_runtime.h>
#include <hip/hip_bf16.h>
#include <stdint.h>

#define HIDDEN 1024
#define NHEADS 16
#define DHEAD  64
#define BATCH  2
#define SEQ    2048
#define MROWS  (BATCH*SEQ)   // 4096
#define QKVC   (3*HIDDEN)    // 3072

typedef unsigned short u16;
typedef unsigned int   u32;
typedef __bf16 bf16x8 __attribute__((ext_vector_type(8)));
typedef __bf16 bf16x2 __attribute__((ext_vector_type(2)));
typedef float  f32x4  __attribute__((ext_vector_type(4)));
typedef float  f32x16 __attribute__((ext_vector_type(16)));
typedef short  s16x4  __attribute__((ext_vector_type(4)));
typedef u16    u16x8  __attribute__((ext_vector_type(8)));
typedef u32    u32x2  __attribute__((ext_vector_type(2)));

typedef const __attribute__((address_space(1))) void gvoid_t;
typedef       __attribute__((address_space(3))) void lvoid_t;

__device__ __forceinline__ gvoid_t* to_glob(const void* p){
  return (gvoid_t*)(uintptr_t)p;
}
__device__ __forceinline__ lvoid_t* to_lds(void* p){
  return (lvoid_t*)(uintptr_t)p;
}
__device__ __forceinline__ u32 lds_off(const void* p){
  return (u32)(uintptr_t)p;
}

// native f32->bf16 (hardware RNE cvt on gfx950)
__device__ __forceinline__ u16 f2bf(float x){
  __bf16 h = (__bf16)x;
  return __builtin_bit_cast(u16, h);
}
// packed f32x2 -> bf16x2 word (compiler emits v_cvt_pk_bf16_f32)
__device__ __forceinline__ u32 pk2(float a, float b){
  bf16x2 t = { (__bf16)a, (__bf16)b };
  return __builtin_bit_cast(u32, t);
}

#define MFMA32(a, b, c) __builtin_amdgcn_mfma_f32_32x32x16_bf16(a, b, c, 0, 0, 0)

// ---------------- fp32 -> bf16 conversion ----------------
__global__ __launch_bounds__(256) void k_cvt(const float* __restrict__ in,
                                             u16* __restrict__ out, int n4){
  int i = blockIdx.x * 256 + threadIdx.x;
  if (i >= n4) return;
  const float4 v = reinterpret_cast<const float4*>(in)[i];
  ushort4 o;
  o.x = f2bf(v.x); o.y = f2bf(v.y); o.z = f2bf(v.z); o.w = f2bf(v.w);
  reinterpret_cast<ushort4*>(out)[i] = o;
}

// ---------------- bf16 GEMM, C = A * B^T + bias (unchanged) ----------------
template<int NC, bool BF16OUT>
__global__ __launch_bounds__(256) void k_gemm(const u16* __restrict__ A,
                                              const u16* __restrict__ B,
                                              const float* __restrict__ bias,
                                              void* __restrict__ C){
  constexpr int K = HIDDEN;
  __shared__ u16 As[2][128*32];
  __shared__ u16 Bs[2][128*32];
  const int m0 = blockIdx.x * 128;
  const int n0 = blockIdx.y * 128;
  const int tid = threadIdx.x;
  const int w = tid >> 6, l = tid & 63;
  const int wr = w >> 1, wc = w & 1;

  const f32x4 fz = {0.f, 0.f, 0.f, 0.f};
  f32x4 acc[4][4];
  #pragma unroll
  for (int i = 0; i < 4; ++i)
    #pragma unroll
    for (int j = 0; j < 4; ++j) acc[i][j] = fz;

  const u16* ap = A + (size_t)(m0 + (tid >> 2)) * K + (tid & 3) * 8;
  const u16* bp = B + (size_t)(n0 + (tid >> 2)) * K + (tid & 3) * 8;

  auto stage = [&](int k0, int buf){
    __builtin_amdgcn_global_load_lds(to_glob(ap + k0),        to_lds(&As[buf][w*512]),        16, 0, 0);
    __builtin_amdgcn_global_load_lds(to_glob(ap + 64*K + k0), to_lds(&As[buf][2048 + w*512]), 16, 0, 0);
    __builtin_amdgcn_global_load_lds(to_glob(bp + k0),        to_lds(&Bs[buf][w*512]),        16, 0, 0);
    __builtin_amdgcn_global_load_lds(to_glob(bp + 64*K + k0), to_lds(&Bs[buf][2048 + w*512]), 16, 0, 0);
  };

  stage(0, 0);
  __syncthreads();

  for (int k0 = 0; k0 < K; k0 += 32){
    const int cur = (k0 >> 5) & 1;
    if (k0 + 32 < K) stage(k0 + 32, cur ^ 1);

    bf16x8 af[4], bfr[4];
    #pragma unroll
    for (int mf = 0; mf < 4; ++mf)
      af[mf]  = *(const bf16x8*)&As[cur][(wr*64 + mf*16 + (l & 15))*32 + (l >> 4)*8];
    #pragma unroll
    for (int nf = 0; nf < 4; ++nf)
      bfr[nf] = *(const bf16x8*)&Bs[cur][(wc*64 + nf*16 + (l & 15))*32 + (l >> 4)*8];
    #pragma unroll
    for (int mf = 0; mf < 4; ++mf)
      #pragma unroll
      for (int nf = 0; nf < 4; ++nf)
        acc[mf][nf] = __builtin_amdgcn_mfma_f32_16x16x32_bf16(af[mf], bfr[nf], acc[mf][nf], 0, 0, 0);

    __syncthreads();
  }

  #pragma unroll
  for (int nf = 0; nf < 4; ++nf){
    const int col = n0 + wc*64 + nf*16 + (l & 15);
    const float bv = bias[col];
    #pragma unroll
    for (int mf = 0; mf < 4; ++mf){
      #pragma unroll
      for (int r = 0; r < 4; ++r){
        const int row = m0 + wr*64 + mf*16 + (l >> 4)*4 + r;
        const float v = acc[mf][nf][r] + bv;
        if constexpr (BF16OUT) ((u16*)C)[(size_t)row * NC + col] = f2bf(v);
        else                   ((float*)C)[(size_t)row * NC + col] = v;
      }
    }
  }
}

// ---------------- causal flash attention: in-block split-K, KVBLK=32 ----
// grid = (32 bh, 32 qt LPT), block 256 = 4 waves (hr = k-half, wr = q-half).
// 32 KiB LDS/block + launch_bounds(256,4) -> 4 blocks/CU = 4 waves/SIMD
// (R7 was LDS-capped at 2). Both K AND V staged via global_load_lds; V's
// global source is pre-swizzled through the inverse subtile map so the
// linear DMA write lands in ds_read_b64_tr_b16 layout (rule #21).
// Units of 32 k-rows; halves each own exactly qt+1 units (uniform trips).
__global__ __launch_bounds__(256, 4) void k_attn(const u16* __restrict__ qkv,
                                                 u16* __restrict__ aout){
  __shared__ u16 smem[16384];   // 32 KiB: per half 16KB = K dbuf 2x4KB | V dbuf 2x4KB

  const int bh = blockIdx.x;
  const int b  = bh >> 4;
  const int h  = bh & 15;
  const int qt = 31 - blockIdx.y;          // LPT: longest blocks first
  const int tid = threadIdx.x;
  const int l  = tid & 63;
  const int w  = tid >> 6;
  const int hr = w >> 1;                   // k-half (0 or 1)
  const int wr = w & 1;                    // q-row half within tile
  const int t128 = tid & 127;
  const int lw = t128 >> 6;                // wave-within-half
  const int U  = qt + 1;                   // 32-k units per half (uniform!)
  const int kb = hr ? U : 0;               // my first unit
  const int q0 = qt*64 + wr*32;            // this wave's 32 q-rows
  const size_t base = (size_t)b * SEQ * QKVC + (size_t)h * 192;
  const float CEXP = 0.18033688011112042f; // 0.125 * log2(e)

  u16* const Kreg = smem + hr*8192;          // + cb*2048 (u16)
  u16* const Vreg = smem + hr*8192 + 4096;   // + cb*2048 (u16)

  // ---- per-lane staging source bases (unit-0); advance by unit*32*QKVC
  // K: lane covers row (t128>>3) + t*16, chunk cg (XOR pre-swizzle)
  const int cgK = (t128 & 7) ^ ((t128 >> 3) & 7);
  const u16* const baseK = qkv + base + (size_t)(t128 >> 3) * QKVC + 64 + cgK * 8;
  // V: inverse subtile map of dest element 8*(t*128+t128):
  //   k = t*16 + (t128>>5)*4 + ((t128>>1)&3); d0 = ((t128>>3)&3)*16 + (t128&1)*8
  const int vk = ((t128 >> 5) << 2) | ((t128 >> 1) & 3);
  const int vd = (((t128 >> 3) & 3) << 4) | ((t128 & 1) << 3);
  const u16* const baseV = qkv + base + (size_t)vk * QKVC + 128 + vd;

  auto stage = [&](int u, int cb){
    const u16* pk = baseK + (size_t)u * 32 * QKVC;
    const u16* pv = baseV + (size_t)u * 32 * QKVC;
    #pragma unroll
    for (int t = 0; t < 2; ++t){
      __builtin_amdgcn_global_load_lds(to_glob(pk + t*16*QKVC),
                                       to_lds(&Kreg[cb*2048 + t*1024 + lw*512]), 16, 0, 0);
      __builtin_amdgcn_global_load_lds(to_glob(pv + t*16*QKVC),
                                       to_lds(&Vreg[cb*2048 + t*1024 + lw*512]), 16, 0, 0);
    }
  };

  // Q B-frags: col=q=(l&31), k-dim=d=(l>>5)*8 + dd*16 + j
  bf16x8 qf[4];
  {
    const u16* qp = qkv + base + (size_t)(q0 + (l & 31)) * QKVC + (l >> 5) * 8;
    #pragma unroll
    for (int dd = 0; dd < 4; ++dd) qf[dd] = *(const bf16x8*)(qp + dd*16);
  }

  f32x16 o0{}, o1{};              // O[q=row(r)][d=(l&31)+{0,32}]
  float m = -1e30f, lsum = 0.f;   // per-lane (q = l&31, own k-rows)

  stage(kb, 0);                   // prologue: my first unit -> buf 0
  __syncthreads();

  const u32 vbase = lds_off(Vreg) + (l & 15)*8 + ((l >> 4) & 1)*128 + (l >> 5)*1024;

  for (int it = 0; it < U; ++it){
    const int cur = it & 1;
    const int u = kb + it;
    if (it + 1 < U) stage(kb + it + 1, cur ^ 1);   // prefetch overlaps compute

    // ---- QK^T: S^T[k 0..31][q], 4 MFMA
    f32x16 a0{};
    const int r0 = l & 31;
    #pragma unroll
    for (int dd = 0; dd < 4; ++dd){
      const int c = dd*2 + (l >> 5);
      const bf16x8 k0 = *(const bf16x8*)&Kreg[cur*2048 + r0*64 + ((c ^ (r0 & 7)))*8];
      a0 = MFMA32(k0, qf[dd], a0);
    }

    // ---- causal mask (units reaching past the wave's first q-row)
    if (u*32 + 31 > q0){
      const int qg = q0 + (l & 31);
      #pragma unroll
      for (int r = 0; r < 16; ++r){
        const int kg = u*32 + (r & 3) + 8*(r >> 2) + 4*(l >> 5);
        if (kg > qg) a0[r] = -1e30f;
      }
    }

    // ---- row-max
    float pm = -1e30f;
    #pragma unroll
    for (int r = 0; r < 16; ++r) pm = fmaxf(pm, a0[r]);
    pm = fmaxf(pm, __shfl(pm, l ^ 32));

    // ---- issue all 8 tr_reads; softmax below hides LDS latency
    s16x4 tr[8];
    {
      const u32 vb = vbase + (cur ? 4096u : 0u);
      #pragma unroll
      for (int kk = 0; kk < 2; ++kk){
        asm volatile("ds_read_b64_tr_b16 %0, %4 offset:0\n\t"
                     "ds_read_b64_tr_b16 %1, %4 offset:512\n\t"
                     "ds_read_b64_tr_b16 %2, %4 offset:256\n\t"
                     "ds_read_b64_tr_b16 %3, %4 offset:768"
                     : "=&v"(tr[kk*4+0]), "=&v"(tr[kk*4+1]),
                       "=&v"(tr[kk*4+2]), "=&v"(tr[kk*4+3])
                     : "v"(vb + kk*2048));
      }
    }

    if (__any(pm > m + 64.f)){            // T13 defer-max
      const float mn = fmaxf(m, pm);
      const float corr = exp2f((m - mn) * CEXP);
      m = mn;
      lsum *= corr;
      #pragma unroll
      for (int r = 0; r < 16; ++r){
        const int row = (r & 3) + 8*(r >> 2) + 4*(l >> 5);
        const float cr = __shfl(corr, row | (l & 32));
        o0[r] *= cr; o1[r] *= cr;
      }
    }
    #pragma unroll
    for (int r = 0; r < 16; ++r){
      const float p = exp2f((a0[r] - m) * CEXP);
      lsum += p;
      a0[r] = p;
    }

    // ---- wait V once, then PV: A-frag via cvt_pk + permlane32_swap
    asm volatile("s_waitcnt lgkmcnt(0)" ::: "memory");
    __builtin_amdgcn_sched_barrier(0);
    #pragma unroll
    for (int kk = 0; kk < 2; ++kk){
      const int o = kk * 8;
      const u32 x0 = pk2(a0[o+0], a0[o+1]);
      const u32 x1 = pk2(a0[o+2], a0[o+3]);
      const u32 y0 = pk2(a0[o+4], a0[o+5]);
      const u32 y1 = pk2(a0[o+6], a0[o+7]);
      const u32x2 r0v = __builtin_amdgcn_permlane32_swap(x0, y0, false, false);
      const u32x2 r1v = __builtin_amdgcn_permlane32_swap(x1, y1, false, false);
      union { u32 wd[4]; bf16x8 v; } af;
      af.wd[0] = r0v[0]; af.wd[1] = r1v[0]; af.wd[2] = r0v[1]; af.wd[3] = r1v[1];
      union { s16x4 hh[2]; bf16x8 v; } b0, b1;
      b0.hh[0] = tr[kk*4+0]; b0.hh[1] = tr[kk*4+1];
      b1.hh[0] = tr[kk*4+2]; b1.hh[1] = tr[kk*4+3];
      o0 = MFMA32(af.v, b0.v, o0);
      o1 = MFMA32(af.v, b1.v, o1);
    }

    __syncthreads();   // drains prefetch DMA + protects buf reuse
  }

  // ---- cross-half merge (once): staging LDS is dead, reuse it
  lsum += __shfl(lsum, l ^ 32);             // combine lane k-halves (same q)
  float* const Osh  = (float*)smem;                         // 16 KB
  float2* const MLsh = (float2*)((char*)smem + 16384);      // 1 KB

  if (hr == 1){
    #pragma unroll
    for (int r = 0; r < 16; ++r){
      Osh[wr*2048 + l*32 + r]      = o0[r];
      Osh[wr*2048 + l*32 + 16 + r] = o1[r];
    }
    MLsh[wr*64 + l] = float2{m, lsum};
  }
  __syncthreads();

  if (hr == 0){
    const float2 ml1 = MLsh[wr*64 + l];
    const float mm = fmaxf(m, ml1.x);
    const float c0 = exp2f((m - mm) * CEXP);
    const float c1 = exp2f((ml1.x - mm) * CEXP);
    const float lm = lsum*c0 + ml1.y*c1;    // >0 always (half-0 non-empty)
    const float a0q = c0 / lm;
    const float a1q = c1 / lm;
    #pragma unroll
    for (int r = 0; r < 16; ++r){
      const int row = (r & 3) + 8*(r >> 2) + 4*(l >> 5);
      const float f0 = __shfl(a0q, row | (l & 32));
      const float f1 = __shfl(a1q, row | (l & 32));
      const int qg = q0 + row;
      u16* op = aout + (size_t)(b*SEQ + qg) * HIDDEN + h*64 + (l & 31);
      op[0]  = f2bf(o0[r]*f0 + Osh[wr*2048 + l*32 + r]*f1);
      op[32] = f2bf(o1[r]*f0 + Osh[wr*2048 + l*32 + 16 + r]*f1);
    }
  }
}

// ---------------- launch ----------------
extern "C" void kernel_launch(void* const* d_in, const int* in_sizes, int n_in,
                              void* d_out, int out_size, void* d_ws, size_t ws_size,
                              hipStream_t stream){
  const float* enc    = (const float*)d_in[0];
  const float* attn_w = (const float*)d_in[1];
  const float* attn_b = (const float*)d_in[2];
  const float* out_w  = (const float*)d_in[3];
  const float* out_b  = (const float*)d_in[4];

  char* ws = (char*)d_ws;
  u16* enc_bf = (u16*)(ws);
  u16* wa_bf  = (u16*)(ws + (size_t)( 8u << 20));
  u16* wo_bf  = (u16*)(ws + (size_t)(14u << 20));
  u16* qkv    = (u16*)(ws + (size_t)(16u << 20));
  u16* aout   = enc_bf;  // safe alias: attn runs strictly after GEMM1

  k_cvt<<<dim3((MROWS*HIDDEN/4 + 255)/256), 256, 0, stream>>>(enc,    enc_bf, MROWS*HIDDEN/4);
  k_cvt<<<dim3((QKVC*HIDDEN/4  + 255)/256), 256, 0, stream>>>(attn_w, wa_bf,  QKVC*HIDDEN/4);
  k_cvt<<<dim3((HIDDEN*HIDDEN/4+ 255)/256), 256, 0, stream>>>(out_w,  wo_bf,  HIDDEN*HIDDEN/4);

  k_gemm<QKVC,  true ><<<dim3(MROWS/128, QKVC/128),  256, 0, stream>>>(enc_bf, wa_bf, attn_b, qkv);
  k_attn<<<dim3(32, 32), 256, 0, stream>>>(qkv, aout);
  k_gemm<HIDDEN, false><<<dim3(MROWS/128, HIDDEN/128), 256, 0, stream>>>(aout, wo_bf, out_b, d_out);
}